// Round 6
// baseline (2485.957 us; speedup 1.0000x reference)
//
#include <hip/hip_runtime.h>
#include <hip/hip_bf16.h>
#include <stdint.h>

// SimpleRNN: B=64, S=512, H=1024, V=128
// Phase 1 (R20): HALVED-EXCHANGE recurrence — 16 wgs x 64 cols, W in VGPRs.
//   Theory: step time = sync legs + exchange_volume/fabric_BW. R13/R14/R15
//   all moved sync mechanics at constant 4 MB/step volume -> identical times;
//   R18/R19 added volume -> proportionally worse. This round halves the
//   volume: 16 col-groups (not 32) => h replicated 16x = 2 MB/step.
//   W_hh slice (64 cols) lives in VGPRs (32 B-frags = 128 VGPR/wave, packed
//   by the PROVEN ldsW formula); LDS = full-h stage (128 KB, removes n-dup)
//   + 16 KB reduce = 144 KB. Waves: 2m x 2n x 2k, 32 MFMA each, A-frags
//   ds_read from staged h at the proven fragment addresses.
//   Sync = R13-PROVEN protocol verbatim: per-wg flags, syncthreads-drain
//   arrival, bounded lane-parallel poll (16 flags), triple-gen h buffers.
// Phase 2: logits GEMM (hidden bf16 @ W_out bf16, 32x32x16 MFMA) + b_out.

#define Bz 64
#define Sz 512
#define Hz 1024
#define Vz 128
#define NWG 16    // col-groups
#define COLS 64   // columns of W_hh per workgroup
#define WGT 512   // 8 waves = 2m x 2n x 2k

typedef __attribute__((ext_vector_type(8)))  short short8;
typedef __attribute__((ext_vector_type(16))) float f32x16;
typedef __attribute__((ext_vector_type(4)))  float f32x4;
typedef __attribute__((ext_vector_type(4)))  unsigned u32x4;   // asm-friendly 16B

// h TRIPLE buffer in MFMA A-fragment order:
// g_hx2[gen][mt][kb=k>>4][slot=((k>>3)&1)*32+(m&31)][j=k&7]   (3 x 128 KB)
__device__ __align__(16) unsigned short g_hx2[3][2][64][64][8];
// hidden states, fragment order per step: [s][mt][kb][slot][8]  (64 MB)
__device__ __align__(16) unsigned short g_hidden[(size_t)Sz*2*64*64*8];
// W_out packed for 32x32x16 B-frags: [kb][nt][lane][8]  (256 KB)
__device__ __align__(16) unsigned short g_wout[64*4*64*8];

__device__ __forceinline__ unsigned short f2bf(float f) {
  union { float f; unsigned u; } v; v.f = f;
  unsigned r = v.u + 0x7FFFu + ((v.u >> 16) & 1u);      // RNE
  return (unsigned short)(r >> 16);
}

__device__ __forceinline__ float fast_tanh(float x) {
  float cx = fminf(9.0f, fmaxf(-9.0f, x));
  float e  = __builtin_amdgcn_exp2f(cx * 2.88539008178f);   // e^(2x)
  return (e - 1.0f) * __builtin_amdgcn_rcpf(e + 1.0f);
}

// 16 coherent (sc1 -> L3) 16-B loads, NO drain — pipeline issue stage.
// Covers 16 KB linear (16 x 1 KB wave reads, lane stride 16 B). [R14-proven]
__device__ __forceinline__ void load16_nodrain(const unsigned short* p0, u32x4 t[16]) {
  const unsigned short* p1 = p0 + 2048;   // +4096 B
  const unsigned short* p2 = p0 + 4096;   // +8192 B
  const unsigned short* p3 = p0 + 6144;   // +12288 B
  asm volatile(
    "global_load_dwordx4 %0,  %16, off sc1\n\t"
    "global_load_dwordx4 %1,  %16, off offset:1024 sc1\n\t"
    "global_load_dwordx4 %2,  %16, off offset:2048 sc1\n\t"
    "global_load_dwordx4 %3,  %16, off offset:3072 sc1\n\t"
    "global_load_dwordx4 %4,  %17, off sc1\n\t"
    "global_load_dwordx4 %5,  %17, off offset:1024 sc1\n\t"
    "global_load_dwordx4 %6,  %17, off offset:2048 sc1\n\t"
    "global_load_dwordx4 %7,  %17, off offset:3072 sc1\n\t"
    "global_load_dwordx4 %8,  %18, off sc1\n\t"
    "global_load_dwordx4 %9,  %18, off offset:1024 sc1\n\t"
    "global_load_dwordx4 %10, %18, off offset:2048 sc1\n\t"
    "global_load_dwordx4 %11, %18, off offset:3072 sc1\n\t"
    "global_load_dwordx4 %12, %19, off sc1\n\t"
    "global_load_dwordx4 %13, %19, off offset:1024 sc1\n\t"
    "global_load_dwordx4 %14, %19, off offset:2048 sc1\n\t"
    "global_load_dwordx4 %15, %19, off offset:3072 sc1"
    : "=&v"(t[0]), "=&v"(t[1]), "=&v"(t[2]),  "=&v"(t[3]),
      "=&v"(t[4]), "=&v"(t[5]), "=&v"(t[6]),  "=&v"(t[7]),
      "=&v"(t[8]), "=&v"(t[9]), "=&v"(t[10]), "=&v"(t[11]),
      "=&v"(t[12]),"=&v"(t[13]),"=&v"(t[14]), "=&v"(t[15])
    : "v"(p0), "v"(p1), "v"(p2), "v"(p3)
    : "memory");
}

// agent-scope write-through store (visible at L3 once vmcnt retires)
__device__ __forceinline__ void store16_sc1(unsigned short* p, u32x4 v) {
  asm volatile("global_store_dwordx4 %0, %1, off sc1" :: "v"(p), "v"(v) : "memory");
}

// ---- Phase 0: pack W_out (H,V) fp32 -> [kb][nt][lane][8] bf16 (32x32 B-frag) --
__global__ void pack_wout(const float* __restrict__ W_out) {
  int gid = blockIdx.x * blockDim.x + threadIdx.x;      // 0..16383
  int lane = gid & 63;
  int nt   = (gid >> 6) & 3;
  int kb   = gid >> 8;
  int n = nt * 32 + (lane & 31);
  int k0 = kb * 16 + (lane >> 5) * 8;
  unsigned short t[8];
#pragma unroll
  for (int j = 0; j < 8; ++j)
    t[j] = f2bf(W_out[(size_t)(k0 + j) * Vz + n]);
  uint4 w;
  w.x = (unsigned)t[0] | ((unsigned)t[1] << 16);
  w.y = (unsigned)t[2] | ((unsigned)t[3] << 16);
  w.z = (unsigned)t[4] | ((unsigned)t[5] << 16);
  w.w = (unsigned)t[6] | ((unsigned)t[7] << 16);
  *(uint4*)&g_wout[(size_t)gid * 8] = w;
}

// ---------------- Phase 1: persistent recurrence -----------------------------
__global__ __launch_bounds__(WGT, 2) void rnn_persistent(
    const int* __restrict__ x, const float* __restrict__ h0,
    const float* __restrict__ W_xh, const float* __restrict__ W_hh,
    const float* __restrict__ b_h, float* __restrict__ out,
    unsigned* __restrict__ flags)
{
  // full-h stage, SAME layout as g_hx2 gen: [mt][kb][slot][8]   (128 KB)
  __shared__ unsigned short hstage[2 * 64 * 64 * 8];
  // k-split partials/final: [region=2mt+nt][r2][lane][4 f32]    (16 KB)
  __shared__ float red[4 * 1024];
  // 144 KB total -> 1 wg per CU

  const int g    = blockIdx.x;        // 0..15
  const int n0g  = g * COLS;
  const int tid  = threadIdx.x;
  const int lane = tid & 63;
  const int ki   = tid >> 6;          // wave 0..7
  const int mt   = ki >> 2;           // M-tile (rows mt*32..+32)
  const int nt   = (ki >> 1) & 1;     // N-tile within wg (cols nt*32..+32)
  const int kt   = ki & 1;            // K-split (512 each)

  // ---- W_hh B-frags -> VGPRs (one-time; PROVEN ldsW packing formula) ----
  // frag ks: k = kt*512 + ks*16 + (lane>>5)*8 + j ; col = n0g + nt*32 + (lane&31)
  short8 wfrag[32];
  {
    const int col = n0g + nt * 32 + (lane & 31);
    const float* wbase = &W_hh[(size_t)(kt * 512 + (lane >> 5) * 8) * Hz + col];
#pragma unroll
    for (int ks = 0; ks < 32; ++ks) {
      const float* wp_ = wbase + (size_t)ks * 16 * Hz;
      unsigned short tt[8];
#pragma unroll
      for (int j = 0; j < 8; ++j) tt[j] = f2bf(wp_[(size_t)j * Hz]);
      short8 w;
      w[0] = (short)tt[0]; w[1] = (short)tt[1]; w[2] = (short)tt[2]; w[3] = (short)tt[3];
      w[4] = (short)tt[4]; w[5] = (short)tt[5]; w[6] = (short)tt[6]; w[7] = (short)tt[7];
      wfrag[ks] = w;
    }
  }

  // ---- h0 -> g_hx2[0]; wg g stages 16B units [g*512, g*512+512) of 8192 ----
  {
    int u = g * 512 + tid;
    int slot = u & 63, plane = u >> 6;          // plane 0..127
    int kb = plane & 63, fmt = plane >> 6;
    int m  = fmt * 32 + (slot & 31);
    int k0 = kb * 16 + (slot >> 5) * 8;
    const float* src = &h0[(size_t)m * Hz + k0];
    float4 a0 = *(const float4*)&src[0];
    float4 a1 = *(const float4*)&src[4];
    u32x4 w;
    w.x = (unsigned)f2bf(a0.x) | ((unsigned)f2bf(a0.y) << 16);
    w.y = (unsigned)f2bf(a0.z) | ((unsigned)f2bf(a0.w) << 16);
    w.z = (unsigned)f2bf(a1.x) | ((unsigned)f2bf(a1.y) << 16);
    w.w = (unsigned)f2bf(a1.z) | ((unsigned)f2bf(a1.w) << 16);
    store16_sc1(&((unsigned short*)g_hx2)[(size_t)u * 8], w);
  }
  __syncthreads();                     // drains h0 stores (R13-proven arrival)
  if (tid == 0)
    __hip_atomic_store(&flags[g * 8], 1u, __ATOMIC_RELAXED,
                       __HIP_MEMORY_SCOPE_AGENT);

  // epilogue mapping: 512 threads -> (row er 0..63, col-octet jo 0..7)
  const int er  = tid & 63;
  const int jo  = tid >> 6;
  const int rr  = er & 31, emt = er >> 5, ent = jo >> 2;
  const int reg = (rr & 3) + 4 * (rr >> 3);
  const int lh  = (rr >> 2) & 1;
  const int redbase = (emt * 2 + ent) * 1024 + (reg >> 2) * 256 +
                      ((jo & 3) * 8 + 32 * lh) * 4 + (reg & 3);
  const int kbE   = g * 4 + (jo >> 1);
  const int slotE = (jo & 1) * 32 + rr;
  const size_t exOff  = (((size_t)emt * 64 + kbE) * 64 + slotE) * 8;   // shorts
  const size_t hidOff = exOff;                    // same [mt][kb][slot][8] form
  float bias[8];
#pragma unroll
  for (int j = 0; j < 8; ++j) bias[j] = b_h[n0g + jo * 8 + j];

  // prefetch step-0 token + 8-wide embedding slice
  int tok_n = x[er * Sz];
  float4 xa_n = *(const float4*)&W_xh[(size_t)tok_n * Hz + n0g + jo * 8];
  float4 xb_n = *(const float4*)&W_xh[(size_t)tok_n * Hz + n0g + jo * 8 + 4];

  const int stbase = ki * 1024;                   // 16B units in hstage
  const short8* hs8 = (const short8*)hstage;
  u32x4* hsv = (u32x4*)hstage;
  const int abase = (mt * 64 + kt * 32) * 64;     // short8 units

  int rp = 0;                               // read generation = s % 3
  for (int s = 0; s < Sz; ++s) {
    const int wp = (rp == 2) ? 0 : rp + 1;  // write generation
    const unsigned tgt = (unsigned)(s + 1); // producers' step-s data flag

    // ---- poll 16 wg flags (R13-proven bounded lane-parallel spin) ----
    {
      const int bound = (s == 0) ? 131072 : 16384;
      for (int it = 0; it < bound; ++it) {
        unsigned v = 0xFFFFFFFFu;
        if (lane < NWG)
          v = __hip_atomic_load(&flags[lane * 8], __ATOMIC_RELAXED,
                                __HIP_MEMORY_SCOPE_AGENT);
        if (__all(v >= tgt)) break;
        __builtin_amdgcn_s_sleep(1);
      }
      asm volatile("" ::: "memory");
    }
    __syncthreads();   // BAR-S1: prev step's hstage reads done on all waves

    // ---- stage this wave's 16 KB chunk: global -> regs -> LDS ----
    u32x4 t[16];
    load16_nodrain(((const unsigned short*)g_hx2) + (size_t)rp * 65536 +
                       ki * 8192 + lane * 8, t);
#define STG(J, CNT)                                                            \
    { asm volatile("s_waitcnt vmcnt(" #CNT ")"                                 \
                   : "+v"(t[4*(J)]), "+v"(t[4*(J)+1]),                         \
                     "+v"(t[4*(J)+2]), "+v"(t[4*(J)+3]));                      \
      hsv[stbase + (4*(J)+0) * 64 + lane] = t[4*(J)+0];                        \
      hsv[stbase + (4*(J)+1) * 64 + lane] = t[4*(J)+1];                        \
      hsv[stbase + (4*(J)+2) * 64 + lane] = t[4*(J)+2];                        \
      hsv[stbase + (4*(J)+3) * 64 + lane] = t[4*(J)+3]; }
    STG(0, 12) STG(1, 8) STG(2, 4) STG(3, 0)
#undef STG
    __syncthreads();   // BAR-S2: full h staged

    // ---- MFMA: 32 x {ds_read_b128 A-frag, mfma} ; 2 independent chains ----
    f32x16 acc0 = {}, acc1 = {};
#pragma unroll
    for (int ks = 0; ks < 32; ks += 2) {
      short8 a0 = hs8[abase + (ks + 0) * 64 + lane];
      short8 a1 = hs8[abase + (ks + 1) * 64 + lane];
      acc0 = __builtin_amdgcn_mfma_f32_32x32x16_bf16(a0, wfrag[ks],     acc0, 0, 0, 0);
      acc1 = __builtin_amdgcn_mfma_f32_32x32x16_bf16(a1, wfrag[ks + 1], acc1, 0, 0, 0);
    }
#pragma unroll
    for (int r = 0; r < 16; ++r) acc0[r] += acc1[r];

    // prefetch NEXT step's token + embedding slice (hides gather latency)
    float4 xa = xa_n, xb = xb_n;
    if (s + 1 < Sz) {
      int t2 = x[er * Sz + s + 1];
      xa_n = *(const float4*)&W_xh[(size_t)t2 * Hz + n0g + jo * 8];
      xb_n = *(const float4*)&W_xh[(size_t)t2 * Hz + n0g + jo * 8 + 4];
    }

    // ---- 2-way K reduce through red (16 KB) ----
    if (kt == 1) {
      const int rb = (mt * 2 + nt) * 1024;
#pragma unroll
      for (int r2 = 0; r2 < 4; ++r2) {
        f32x4 w = {acc0[4*r2], acc0[4*r2+1], acc0[4*r2+2], acc0[4*r2+3]};
        *(f32x4*)&red[rb + r2 * 256 + lane * 4] = w;
      }
    }
    __syncthreads();   // BAR-R1: k=1 partials visible
    if (kt == 0) {
      const int rb = (mt * 2 + nt) * 1024;
#pragma unroll
      for (int r2 = 0; r2 < 4; ++r2) {
        f32x4 p = *(const f32x4*)&red[rb + r2 * 256 + lane * 4];
        f32x4 w = {acc0[4*r2] + p.x, acc0[4*r2+1] + p.y,
                   acc0[4*r2+2] + p.z, acc0[4*r2+3] + p.w};
        *(f32x4*)&red[rb + r2 * 256 + lane * 4] = w;
      }
    }
    __syncthreads();   // BAR-R2: final z tiles in red

    // ---- epilogue: 8 cols per thread; z = red + emb + bias; h = tanh(z) ----
    float z[8];
#pragma unroll
    for (int i = 0; i < 8; ++i) z[i] = red[redbase + i * 4];
    z[0] = fast_tanh(z[0] + xa.x + bias[0]);
    z[1] = fast_tanh(z[1] + xa.y + bias[1]);
    z[2] = fast_tanh(z[2] + xa.z + bias[2]);
    z[3] = fast_tanh(z[3] + xa.w + bias[3]);
    z[4] = fast_tanh(z[4] + xb.x + bias[4]);
    z[5] = fast_tanh(z[5] + xb.y + bias[5]);
    z[6] = fast_tanh(z[6] + xb.z + bias[6]);
    z[7] = fast_tanh(z[7] + xb.w + bias[7]);

    u32x4 w2;
    w2.x = (unsigned)f2bf(z[0]) | ((unsigned)f2bf(z[1]) << 16);
    w2.y = (unsigned)f2bf(z[2]) | ((unsigned)f2bf(z[3]) << 16);
    w2.z = (unsigned)f2bf(z[4]) | ((unsigned)f2bf(z[5]) << 16);
    w2.w = (unsigned)f2bf(z[6]) | ((unsigned)f2bf(z[7]) << 16);

    // h store: one coalesced 16B unit per thread, write-through to L3
    store16_sc1(&((unsigned short*)g_hx2)[(size_t)wp * 65536 + exOff], w2);
    *(u32x4*)&g_hidden[(size_t)s * 65536 + hidOff] = w2;
    if (s == Sz - 1) {
      float* hf = out + (size_t)Bz * Sz * Vz + (size_t)er * Hz + n0g + jo * 8;
      float4 f0 = {z[0], z[1], z[2], z[3]};
      float4 f1 = {z[4], z[5], z[6], z[7]};
      *(float4*)&hf[0] = f0;
      *(float4*)&hf[4] = f1;
    }

    // arrival (R13-proven): syncthreads drains all waves' stores, then tid0
    // publishes the wg flag. Consumer waits happen at next loop top.
    __syncthreads();
    if (tid == 0)
      __hip_atomic_store(&flags[g * 8], (unsigned)(s + 2), __ATOMIC_RELAXED,
                         __HIP_MEMORY_SCOPE_AGENT);
    rp = wp;
  }
}

// ---------------- Phase 2: logits = hidden @ W_out + b_out -------------------
// grid: 1024 blocks = (s, mi); 4 waves; wave nt computes 32 rows x 32 cols, K=1024
__global__ __launch_bounds__(256) void logits_gemm(
    const float* __restrict__ b_out, float* __restrict__ out)
{
  const int tid = threadIdx.x, lane = tid & 63, nt = tid >> 6;
  const int s = blockIdx.x >> 1, mi = blockIdx.x & 1;
  const unsigned short* ab = &g_hidden[((size_t)s * 8192 + (size_t)mi * 4096) * 8];

  f32x16 acc = {};
#pragma unroll 8
  for (int kb = 0; kb < 64; ++kb) {
    short8 a = *(const short8*)&ab[(size_t)(kb * 64 + lane) * 8];
    short8 b = *(const short8*)&g_wout[(size_t)((kb * 4 + nt) * 64 + lane) * 8];
    acc = __builtin_amdgcn_mfma_f32_32x32x16_bf16(a, b, acc, 0, 0, 0);
  }
  const int col = nt * 32 + (lane & 31);
  const float bo = b_out[col];
  const int rbase = 4 * (lane >> 5);
#pragma unroll
  for (int r = 0; r < 16; ++r) {
    int m = rbase + (r & 3) + 8 * (r >> 2);
    int em = mi * 32 + m;
    out[((size_t)em * Sz + s) * Vz + col] = acc[r] + bo;
  }
}

// ---------------- host launcher ----------------------------------------------
extern "C" void kernel_launch(void* const* d_in, const int* in_sizes, int n_in,
                              void* d_out, int out_size, void* d_ws, size_t ws_size,
                              hipStream_t stream) {
  const int*   x     = (const int*)d_in[0];
  const float* h0    = (const float*)d_in[1];
  const float* W_xh  = (const float*)d_in[2];
  const float* W_hh  = (const float*)d_in[3];
  const float* b_h   = (const float*)d_in[4];
  const float* W_out = (const float*)d_in[5];
  const float* b_out = (const float*)d_in[6];
  float* out = (float*)d_out;

  (void)hipMemsetAsync(d_ws, 0, 4096, stream);    // 16 wg-flag lines
  pack_wout<<<64, 256, 0, stream>>>(W_out);
  rnn_persistent<<<NWG, WGT, 0, stream>>>(x, h0, W_xh, W_hh, b_h, out,
                                          (unsigned*)d_ws);
  logits_gemm<<<Sz * 2, 256, 0, stream>>>(b_out, out);
}

// Round 7
// 2160.410 us; speedup vs baseline: 1.1507x; 1.1507x over previous
//
#include <hip/hip_runtime.h>
#include <hip/hip_bf16.h>
#include <stdint.h>

// SimpleRNN: B=64, S=512, H=1024, V=128
// Phase 1 (R21): FLAG-GATED SEQLOCK.
//   Evidence: R14==R15 (3.0us/step regardless of per-CU work) => critical
//   path is pure latency legs; R18 (seqlock) removed producer drain+flag legs
//   but its 16KB/RTT poll sweeps saturated the L3 fabric (FETCH +247MB);
//   R20 (volume halved) regressed => volume not binding.
//   Composition of proven parts:
//     - producer: store {u32 data, u32 seq} via ONE global_store_dwordx2
//       (8B single-copy atomic, R18-proven), then post per-wave flag with
//       NO vmcnt drain (flag = hint only).
//     - consumer: tight-poll 32 producer-wave flags (8 cache lines/wave,
//       R15-cheap), then ONE 16KB seq-validated sweep (R18-proven loader);
//       bounded retry covers the rare flag-beats-data race.
//     - raw s_barrier epilogue barriers (R19-proven) — no per-step
//       __syncthreads vmcnt drains; no arrival barrier at all.
//   64 wgs = 2 batch-halves x 32 col-groups, 8-wave K-split, triple-buffered
//   h, per-launch epoch namespace for seqs.
// Phase 2: logits GEMM (hidden bf16 @ W_out bf16, 32x32x16 MFMA) + b_out.

#define Bz 64
#define Sz 512
#define Hz 1024
#define Vz 128
#define NWG 64    // 2 batch-halves x 32 col-groups
#define COLS 32   // columns of W_hh per workgroup
#define WGT 512   // 8 waves = 8-way K-split (128 k each)

typedef __attribute__((ext_vector_type(8)))  short short8;
typedef __attribute__((ext_vector_type(16))) float f32x16;
typedef __attribute__((ext_vector_type(4)))  unsigned u32x4;   // asm-friendly 16B
typedef __attribute__((ext_vector_type(2)))  unsigned u32x2;   // asm-friendly 8B

__device__ unsigned g_epoch;    // bumped once per launch (pack_wout block0/tid0)

// seq-embedded h exchange, TRIPLE buffer:
// g_hx[gen][bh][kb=k>>4][lane=((k>>3)&1)*32+r][8 words]
//   words = {d0,q, d1,q, d2,q, d3,q}; dw = bf16 cols (2w, 2w+1) of k-octet,
//   q = epoch_base + step + 1.  (768 KB total, L3-resident)
__device__ __align__(16) unsigned g_hx[3][2][64][64][8];
// hidden states, fragment order per step: [s][bh][kb][lane][8]  (64 MB)
__device__ __align__(16) unsigned short g_hidden[(size_t)Sz*2*64*64*8];
// W_out packed for 32x32x16 B-frags: [kb][nt][lane][8]  (256 KB)
__device__ __align__(16) unsigned short g_wout[64*4*64*8];

__device__ __forceinline__ unsigned short f2bf(float f) {
  union { float f; unsigned u; } v; v.f = f;
  unsigned r = v.u + 0x7FFFu + ((v.u >> 16) & 1u);      // RNE
  return (unsigned short)(r >> 16);
}

__device__ __forceinline__ float fast_tanh(float x) {
  float cx = fminf(9.0f, fmaxf(-9.0f, x));
  float e  = __builtin_amdgcn_exp2f(cx * 2.88539008178f);   // e^(2x)
  return (e - 1.0f) * __builtin_amdgcn_rcpf(e + 1.0f);
}

// 16 L3-coherent 16-B loads covering this wave's 8 kb planes (2 units/plane),
// drain INSIDE the asm block (outputs valid on exit — no reorder hazard).
__device__ __forceinline__ void load16_seq(const unsigned* p0, u32x4 t[16]) {
  const unsigned* p1 = p0 + 1024;   // +4096 B (2 planes)
  const unsigned* p2 = p0 + 2048;
  const unsigned* p3 = p0 + 3072;
  asm volatile(
    "global_load_dwordx4 %0,  %16, off sc1\n\t"
    "global_load_dwordx4 %1,  %16, off offset:16 sc1\n\t"
    "global_load_dwordx4 %2,  %16, off offset:2048 sc1\n\t"
    "global_load_dwordx4 %3,  %16, off offset:2064 sc1\n\t"
    "global_load_dwordx4 %4,  %17, off sc1\n\t"
    "global_load_dwordx4 %5,  %17, off offset:16 sc1\n\t"
    "global_load_dwordx4 %6,  %17, off offset:2048 sc1\n\t"
    "global_load_dwordx4 %7,  %17, off offset:2064 sc1\n\t"
    "global_load_dwordx4 %8,  %18, off sc1\n\t"
    "global_load_dwordx4 %9,  %18, off offset:16 sc1\n\t"
    "global_load_dwordx4 %10, %18, off offset:2048 sc1\n\t"
    "global_load_dwordx4 %11, %18, off offset:2064 sc1\n\t"
    "global_load_dwordx4 %12, %19, off sc1\n\t"
    "global_load_dwordx4 %13, %19, off offset:16 sc1\n\t"
    "global_load_dwordx4 %14, %19, off offset:2048 sc1\n\t"
    "global_load_dwordx4 %15, %19, off offset:2064 sc1\n\t"
    "s_waitcnt vmcnt(0)"
    : "=&v"(t[0]), "=&v"(t[1]), "=&v"(t[2]),  "=&v"(t[3]),
      "=&v"(t[4]), "=&v"(t[5]), "=&v"(t[6]),  "=&v"(t[7]),
      "=&v"(t[8]), "=&v"(t[9]), "=&v"(t[10]), "=&v"(t[11]),
      "=&v"(t[12]),"=&v"(t[13]),"=&v"(t[14]), "=&v"(t[15])
    : "v"(p0), "v"(p1), "v"(p2), "v"(p3)
    : "memory");
}

// 8 B single-instruction store (single-copy atomic unit {data, seq})
__device__ __forceinline__ void store8_sc1(unsigned* p, u32x2 v) {
  asm volatile("global_store_dwordx2 %0, %1, off sc1" :: "v"(p), "v"(v) : "memory");
}

// ---- Phase 0: pack W_out (H,V) fp32 -> [kb][nt][lane][8] bf16 (32x32 B-frag) --
__global__ void pack_wout(const float* __restrict__ W_out) {
  if (blockIdx.x == 0 && threadIdx.x == 0) g_epoch = g_epoch + 1u;  // per-launch
  int gid = blockIdx.x * blockDim.x + threadIdx.x;      // 0..16383
  int lane = gid & 63;
  int nt   = (gid >> 6) & 3;
  int kb   = gid >> 8;
  int n = nt * 32 + (lane & 31);
  int k0 = kb * 16 + (lane >> 5) * 8;
  unsigned short t[8];
#pragma unroll
  for (int j = 0; j < 8; ++j)
    t[j] = f2bf(W_out[(size_t)(k0 + j) * Vz + n]);
  uint4 w;
  w.x = (unsigned)t[0] | ((unsigned)t[1] << 16);
  w.y = (unsigned)t[2] | ((unsigned)t[3] << 16);
  w.z = (unsigned)t[4] | ((unsigned)t[5] << 16);
  w.w = (unsigned)t[6] | ((unsigned)t[7] << 16);
  *(uint4*)&g_wout[(size_t)gid * 8] = w;
}

// ---------------- Phase 1: persistent recurrence -----------------------------
__global__ __launch_bounds__(WGT) void rnn_persistent(
    const int* __restrict__ x, const float* __restrict__ h0,
    const float* __restrict__ W_xh, const float* __restrict__ W_hh,
    const float* __restrict__ b_h, float* __restrict__ out,
    unsigned* __restrict__ flags)
{
  // W slice (32 cols): [kb(64)][lane=kq*32+n][8] -> B-frag via ds_read_b128
  __shared__ unsigned short ldsW[64 * 64 * 8];          // 64 KB
  // 8 K-split partial regions, XOR-swizzled: red[ki*1024 + m*32 + (c^m)]
  __shared__ float red[8 * 1024];                       // 32 KB
  // 96 KB total -> 1 wg per CU (proven R14/R15/R18 configuration)

  const int g    = blockIdx.x;        // 0..63
  const int bh   = g >> 5;            // batch half (rows bh*32 .. +32)
  const int cg   = g & 31;            // col-group
  const int n0g  = cg * COLS;         // global column base of W slice
  const int tid  = threadIdx.x;
  const int lane = tid & 63;
  const int ki   = tid >> 6;          // wave = K-split 0..7 (128 k each)
  const int bn   = lane & 31;
  const unsigned epb = g_epoch << 10; // epoch base (seq namespace per launch)

  // ---- stage W_hh[:, n0g : n0g+32) -> ldsW (one-time) ----
  for (int idx = tid; idx < 64 * 64; idx += WGT) {
    int kb = idx >> 6, L = idx & 63;
    int n = L & 31, kq = L >> 5;
    unsigned short t[8];
#pragma unroll
    for (int j = 0; j < 8; ++j)
      t[j] = f2bf(W_hh[(size_t)(kb * 16 + kq * 8 + j) * Hz + n0g + n]);
    uint4 w;
    w.x = (unsigned)t[0] | ((unsigned)t[1] << 16);
    w.y = (unsigned)t[2] | ((unsigned)t[3] << 16);
    w.z = (unsigned)t[4] | ((unsigned)t[5] << 16);
    w.w = (unsigned)t[6] | ((unsigned)t[7] << 16);
    *(uint4*)&ldsW[(size_t)idx * 8] = w;
  }

  // ---- h0 -> g_hx[0] with seq = epb+1; wg g stages units [g*512, +512) ----
  {
    int u  = g * 512 + tid;           // unit = {4B data, 4B seq}
    int w  = u & 3;                   // word-pair within (kb,lane)
    int L  = (u >> 2) & 63;
    int kb = (u >> 8) & 63;
    int fb = (u >> 14) & 1;           // batch half
    int m  = fb * 32 + (L & 31);
    int k  = kb * 16 + (L >> 5) * 8 + w * 2;
    const float* src = &h0[(size_t)m * Hz + k];
    u32x2 v;
    v.x = (unsigned)f2bf(src[0]) | ((unsigned)f2bf(src[1]) << 16);
    v.y = epb + 1u;
    store8_sc1(&g_hx[0][fb][kb][L][2 * w], v);
  }
  __syncthreads();        // ldsW ready (drains h0 stores too — one-time)
  // initial flag hints (value 1), per wave, no extra drain needed
  if (lane == 0)
    __hip_atomic_store(&flags[(g * 8 + ki) * 4], 1u, __ATOMIC_RELAXED,
                       __HIP_MEMORY_SCOPE_AGENT);

  // epilogue mapping: 512 threads -> 32 rows x 16 col-pairs
  const int er   = tid & 31;                  // row within batch half
  const int em   = bh * 32 + er;              // global batch row
  const int c0   = (tid >> 5) * 2;            // col within wg slice (even)
  const int kcol = n0g + c0;                  // global h column
  const int kb_g = kcol >> 4;
  const int kq2  = (kcol >> 3) & 1;
  const int lslot = kq2 * 32 + er;
  const int wq   = (c0 >> 1) & 3;             // unit index within (kb,lane)
  unsigned* exw0 = &g_hx[0][bh][kb_g][lslot][2 * wq];   // + gen*65536 u32s
  const size_t hidOff =
      ((((size_t)bh * 64) + kb_g) * 64 + lslot) * 8 + (kcol & 7);
  const float bias0 = b_h[kcol], bias1 = b_h[kcol + 1];

  // consumer watch list: 32 producer-wave flags (4 producer wgs x 8 waves),
  // lane<32 watches one each  [R15-proven mapping]
  const int pflag =
      ((bh * 32 + ki * 4 + (lane >> 3)) * 8 + (lane & 7)) * 4;

  // prefetch step-0 token + embedding pair
  int tok_n = x[em * Sz];
  float2 xv_n = *(const float2*)&W_xh[(size_t)tok_n * Hz + kcol];

  int rp = 0;                               // read generation = s % 3
  for (int s = 0; s < Sz; ++s) {
    const int wp = (rp == 2) ? 0 : rp + 1;  // write generation
    const unsigned ftgt = (unsigned)(s + 1);       // flag hint value
    const unsigned tgt  = epb + (unsigned)(s + 1); // embedded-seq truth

    // ---- tight flag poll (hint; 8 cache lines/wave, no sleep) ----
    {
      const int bound = (s == 0) ? 131072 : 32768;
      for (int it = 0; it < bound; ++it) {
        unsigned v = 0xFFFFFFFFu;
        if (lane < 32)
          v = __hip_atomic_load(&flags[pflag], __ATOMIC_RELAXED,
                                __HIP_MEMORY_SCOPE_AGENT);
        if (__all(v >= ftgt)) break;
      }
      asm volatile("" ::: "memory");
    }

    // ---- one 16KB sweep + validate embedded seqs (retry rare) ----
    u32x4 t[16];
    {
      const unsigned* hp = &g_hx[rp][bh][ki * 8][lane][0];
      for (int rt = 0; rt < 8192; ++rt) {
        load16_seq(hp, t);                  // includes s_waitcnt vmcnt(0)
        unsigned bad = (t[0].y ^ tgt) | (t[0].w ^ tgt);
#pragma unroll
        for (int i = 1; i < 16; ++i)
          bad |= (t[i].y ^ tgt) | (t[i].w ^ tgt);
        if (__all(bad == 0u)) break;
        __builtin_amdgcn_s_sleep(1);
      }
      asm volatile("" ::: "memory");
    }

    // MFMA over this wave's 8 kb planes; A-frags extracted from data words.
    f32x16 acc0 = {}, acc1 = {};
#pragma unroll
    for (int p = 0; p < 8; p += 2) {
      u32x4 fa, fb2;
      fa.x  = t[2 * p].x;     fa.y  = t[2 * p].z;
      fa.z  = t[2 * p + 1].x; fa.w  = t[2 * p + 1].z;
      fb2.x = t[2 * p + 2].x; fb2.y = t[2 * p + 2].z;
      fb2.z = t[2 * p + 3].x; fb2.w = t[2 * p + 3].z;
      const int kbp = ki * 8 + p;
      short8 ba = *(const short8*)&ldsW[(size_t)(kbp * 64 + lane) * 8];
      short8 bb = *(const short8*)&ldsW[(size_t)((kbp + 1) * 64 + lane) * 8];
      acc0 = __builtin_amdgcn_mfma_f32_32x32x16_bf16(*(short8*)&fa, ba,
                                                     acc0, 0, 0, 0);
      acc1 = __builtin_amdgcn_mfma_f32_32x32x16_bf16(*(short8*)&fb2, bb,
                                                     acc1, 0, 0, 0);
    }

    // prefetch NEXT step's token + embedding pair (floats across raw barriers)
    float2 xv = xv_n;
    if (s + 1 < Sz) {
      int t2 = x[em * Sz + s + 1];
      xv_n = *(const float2*)&W_xh[(size_t)t2 * Hz + kcol];
    }

    // ---- BAR-A (raw): prev step's epilogue reads complete on every wave
    // (each wave consumed them into z before publishing). No vmem drain.
    __builtin_amdgcn_sched_barrier(0);
    __builtin_amdgcn_s_barrier();
    __builtin_amdgcn_sched_barrier(0);

    // C/D: col=lane&31, row=(reg&3)+8*(reg>>2)+4*(lane>>5)  [m74/m101]
    {
#pragma unroll
      for (int r = 0; r < 16; ++r) {
        int m = 4 * (lane >> 5) + (r & 3) + 8 * (r >> 2);
        red[ki * 1024 + m * 32 + (bn ^ m)] = acc0[r] + acc1[r];
      }
    }
    // ---- BAR-B (raw + lgkmcnt): all 8 partials visible in red ----
    asm volatile("s_waitcnt lgkmcnt(0)" ::: "memory");
    __builtin_amdgcn_sched_barrier(0);
    __builtin_amdgcn_s_barrier();
    __builtin_amdgcn_sched_barrier(0);

    // epilogue: z = sum of 8 partials + emb + bias; h = tanh(z)
    float z0, z1;
    {
      const int o0 = er * 32 + (c0 ^ er);
      const int o1 = er * 32 + ((c0 + 1) ^ er);
      z0 = ((red[o0] + red[1024 + o0]) + (red[2048 + o0] + red[3072 + o0])) +
           ((red[4096 + o0] + red[5120 + o0]) + (red[6144 + o0] + red[7168 + o0]));
      z1 = ((red[o1] + red[1024 + o1]) + (red[2048 + o1] + red[3072 + o1])) +
           ((red[4096 + o1] + red[5120 + o1]) + (red[6144 + o1] + red[7168 + o1]));
    }
    z0 = fast_tanh(z0 + xv.x + bias0);
    z1 = fast_tanh(z1 + xv.y + bias1);

    unsigned w2 = (unsigned)f2bf(z0) | ((unsigned)f2bf(z1) << 16);

    // publication = the data store itself ({data, seq} 8B atomic unit)...
    u32x2 v; v.x = w2; v.y = epb + (unsigned)(s + 2);
    store8_sc1(exw0 + (size_t)wp * 65536, v);
    // ...then the flag HINT, immediately, with NO drain (seq is the truth).
    if (lane == 0)
      __hip_atomic_store(&flags[(g * 8 + ki) * 4], (unsigned)(s + 2),
                         __ATOMIC_RELAXED, __HIP_MEMORY_SCOPE_AGENT);

    // off the critical path:
    *(unsigned*)&g_hidden[(size_t)s * 65536 + hidOff] = w2;
    if (s == Sz - 1) {
      float* hf = out + (size_t)Bz * Sz * Vz + (size_t)em * Hz + kcol;
      hf[0] = z0; hf[1] = z1;
    }
    rp = wp;
  }
}

// ---------------- Phase 2: logits = hidden @ W_out + b_out -------------------
// grid: 1024 blocks = (s, mi); 4 waves; wave nt computes 32 rows x 32 cols, K=1024
__global__ __launch_bounds__(256) void logits_gemm(
    const float* __restrict__ b_out, float* __restrict__ out)
{
  const int tid = threadIdx.x, lane = tid & 63, nt = tid >> 6;
  const int s = blockIdx.x >> 1, mi = blockIdx.x & 1;
  const unsigned short* ab = &g_hidden[((size_t)s * 8192 + (size_t)mi * 4096) * 8];

  f32x16 acc = {};
#pragma unroll 8
  for (int kb = 0; kb < 64; ++kb) {
    short8 a = *(const short8*)&ab[(size_t)(kb * 64 + lane) * 8];
    short8 b = *(const short8*)&g_wout[(size_t)((kb * 4 + nt) * 64 + lane) * 8];
    acc = __builtin_amdgcn_mfma_f32_32x32x16_bf16(a, b, acc, 0, 0, 0);
  }
  const int col = nt * 32 + (lane & 31);
  const float bo = b_out[col];
  const int rbase = 4 * (lane >> 5);
#pragma unroll
  for (int r = 0; r < 16; ++r) {
    int m = rbase + (r & 3) + 8 * (r >> 2);
    int em = mi * 32 + m;
    out[((size_t)em * Sz + s) * Vz + col] = acc[r] + bo;
  }
}

// ---------------- host launcher ----------------------------------------------
extern "C" void kernel_launch(void* const* d_in, const int* in_sizes, int n_in,
                              void* d_out, int out_size, void* d_ws, size_t ws_size,
                              hipStream_t stream) {
  const int*   x     = (const int*)d_in[0];
  const float* h0    = (const float*)d_in[1];
  const float* W_xh  = (const float*)d_in[2];
  const float* W_hh  = (const float*)d_in[3];
  const float* b_h   = (const float*)d_in[4];
  const float* W_out = (const float*)d_in[5];
  const float* b_out = (const float*)d_in[6];
  float* out = (float*)d_out;

  (void)hipMemsetAsync(d_ws, 0, 8192, stream);    // 512 per-wave flag slots
  pack_wout<<<64, 256, 0, stream>>>(W_out);       // also bumps g_epoch
  rnn_persistent<<<NWG, WGT, 0, stream>>>(x, h0, W_xh, W_hh, b_h, out,
                                          (unsigned*)d_ws);
  logits_gemm<<<Sz * 2, 256, 0, stream>>>(b_out, out);
}